// Round 1
// baseline (120.662 us; speedup 1.0000x reference)
//
#include <hip/hip_runtime.h>

#define BATCH 16384
#define EMBD 64
#define GLOBAL_MEAN 3.82f

__device__ __forceinline__ int lower_bound(const int* __restrict__ seg, int n, int key) {
    int lo = 0, hi = n;
    while (lo < hi) {
        int mid = (lo + hi) >> 1;
        if (seg[mid] < key) lo = mid + 1; else hi = mid;
    }
    return lo;
}

__global__ __launch_bounds__(256) void svdpp_fwd(
    const int* __restrict__ scientist_ids,
    const int* __restrict__ paper_ids,
    const int* __restrict__ sp_idx, const int* __restrict__ sp_seg, int t_sp,
    const int* __restrict__ sw_idx, const int* __restrict__ sw_seg, int t_sw,
    const float* __restrict__ s_factors,
    const float* __restrict__ p_factors,
    const float* __restrict__ s_bias,
    const float* __restrict__ p_bias,
    const float* __restrict__ imp_f,
    const float* __restrict__ imp_w,
    float* __restrict__ out)
{
    const int wave = (blockIdx.x * blockDim.x + threadIdx.x) >> 6;
    const int lane = threadIdx.x & 63;
    if (wave >= BATCH) return;
    const int row = wave;

    // ---- pooled sum over sp (implicit_factors) ----
    int s0 = lower_bound(sp_seg, t_sp, row);
    int e0 = lower_bound(sp_seg, t_sp, row + 1);
    s0 = __builtin_amdgcn_readfirstlane(s0);
    e0 = __builtin_amdgcn_readfirstlane(e0);
    float acc_sp = 0.f;
    for (int e = s0; e < e0; ++e) {
        int idx = __builtin_amdgcn_readfirstlane(sp_idx[e]);
        acc_sp += imp_f[idx * EMBD + lane];
    }

    // ---- pooled sum over sw (implicit_wishlist) ----
    int s1 = lower_bound(sw_seg, t_sw, row);
    int e1 = lower_bound(sw_seg, t_sw, row + 1);
    s1 = __builtin_amdgcn_readfirstlane(s1);
    e1 = __builtin_amdgcn_readfirstlane(e1);
    float acc_sw = 0.f;
    for (int e = s1; e < e1; ++e) {
        int idx = __builtin_amdgcn_readfirstlane(sw_idx[e]);
        acc_sw += imp_w[idx * EMBD + lane];
    }

    float c0 = (float)(e0 - s0);
    float c1 = (float)(e1 - s1);
    float inv0 = c0 > 0.f ? rsqrtf(c0) : 0.f;
    float inv1 = c1 > 0.f ? rsqrtf(c1) : 0.f;

    const int sid = __builtin_amdgcn_readfirstlane(scientist_ids[row]);
    const int pid = __builtin_amdgcn_readfirstlane(paper_ids[row]);
    float sf = s_factors[sid * EMBD + lane];
    float pf = p_factors[pid * EMBD + lane];

    float v = (sf + acc_sp * inv0 + acc_sw * inv1) * pf;

    // wave-wide sum (64 lanes)
    #pragma unroll
    for (int off = 32; off > 0; off >>= 1)
        v += __shfl_xor(v, off, 64);

    if (lane == 0)
        out[row] = v + s_bias[sid] + p_bias[pid] + GLOBAL_MEAN;
}

extern "C" void kernel_launch(void* const* d_in, const int* in_sizes, int n_in,
                              void* d_out, int out_size, void* d_ws, size_t ws_size,
                              hipStream_t stream) {
    const int* scientist_ids = (const int*)d_in[0];
    const int* paper_ids     = (const int*)d_in[1];
    const int* sp_idx        = (const int*)d_in[2];
    const int* sp_seg        = (const int*)d_in[3];
    const int* sw_idx        = (const int*)d_in[4];
    const int* sw_seg        = (const int*)d_in[5];
    const float* s_factors   = (const float*)d_in[6];
    const float* p_factors   = (const float*)d_in[7];
    const float* s_bias      = (const float*)d_in[8];
    const float* p_bias      = (const float*)d_in[9];
    const float* imp_f       = (const float*)d_in[10];
    const float* imp_w       = (const float*)d_in[11];
    float* out = (float*)d_out;

    const int t_sp = in_sizes[2];
    const int t_sw = in_sizes[4];

    // one wave per batch row; 4 waves per block
    const int blocks = (BATCH * 64) / 256;
    svdpp_fwd<<<blocks, 256, 0, stream>>>(
        scientist_ids, paper_ids,
        sp_idx, sp_seg, t_sp,
        sw_idx, sw_seg, t_sw,
        s_factors, p_factors, s_bias, p_bias,
        imp_f, imp_w, out);
}

// Round 2
// 61.862 us; speedup vs baseline: 1.9505x; 1.9505x over previous
//
#include <hip/hip_runtime.h>

#define BATCH 16384
#define EMBD 64
#define GLOBAL_MEAN 3.82f

// --- preprocessing: turn sorted seg array into per-row [start,end) bounds ---
__global__ __launch_bounds__(256) void seg_bounds_kernel(
    const int* __restrict__ seg, int n, int* __restrict__ start)
{
    int i = blockIdx.x * blockDim.x + threadIdx.x;
    if (i >= n) return;
    int s = seg[i];
    int sprev = (i == 0) ? -1 : seg[i - 1];
    for (int r = sprev + 1; r <= s; ++r) start[r] = i;
    if (i == n - 1)
        for (int r = s + 1; r <= BATCH; ++r) start[r] = n;
}

__device__ __forceinline__ void xor_add4(float4& a, int off) {
    a.x += __shfl_xor(a.x, off, 64);
    a.y += __shfl_xor(a.y, off, 64);
    a.z += __shfl_xor(a.z, off, 64);
    a.w += __shfl_xor(a.w, off, 64);
}

__global__ __launch_bounds__(256) void svdpp_fwd(
    const int* __restrict__ scientist_ids,
    const int* __restrict__ paper_ids,
    const int* __restrict__ sp_idx, const int* __restrict__ sp_start,
    const int* __restrict__ sw_idx, const int* __restrict__ sw_start,
    const float* __restrict__ s_factors,
    const float* __restrict__ p_factors,
    const float* __restrict__ s_bias,
    const float* __restrict__ p_bias,
    const float* __restrict__ imp_f,
    const float* __restrict__ imp_w,
    float* __restrict__ out)
{
    const int wave = (blockIdx.x * blockDim.x + threadIdx.x) >> 6;
    const int lane = threadIdx.x & 63;
    if (wave >= BATCH) return;
    const int row  = wave;
    const int sub  = lane >> 4;   // which of 4 entries this lane helps load
    const int doff = (lane & 15) * 4;  // float4 slot: dims doff..doff+3

    const int s0 = __builtin_amdgcn_readfirstlane(sp_start[row]);
    const int e0 = __builtin_amdgcn_readfirstlane(sp_start[row + 1]);
    const int s1 = __builtin_amdgcn_readfirstlane(sw_start[row]);
    const int e1 = __builtin_amdgcn_readfirstlane(sw_start[row + 1]);
    const int n0 = e0 - s0;
    const int n1 = e1 - s1;
    const int m  = n0 > n1 ? n0 : n1;

    float4 acc0 = {0.f, 0.f, 0.f, 0.f};
    float4 acc1 = {0.f, 0.f, 0.f, 0.f};

    // 4 entries per pool per iteration; both pools interleaved for MLP
    #pragma unroll 2
    for (int k = sub; k < m; k += 4) {
        bool ok0 = k < n0;
        bool ok1 = k < n1;
        int id0 = sp_idx[ok0 ? (s0 + k) : 0];
        int id1 = sw_idx[ok1 ? (s1 + k) : 0];
        float4 v0 = *(const float4*)(imp_f + (size_t)id0 * EMBD + doff);
        float4 v1 = *(const float4*)(imp_w + (size_t)id1 * EMBD + doff);
        if (ok0) { acc0.x += v0.x; acc0.y += v0.y; acc0.z += v0.z; acc0.w += v0.w; }
        if (ok1) { acc1.x += v1.x; acc1.y += v1.y; acc1.z += v1.z; acc1.w += v1.w; }
    }

    // combine the 4 sub-groups: after xor(16) and xor(32) every lane holds
    // the full pooled sum for its 4 dims
    xor_add4(acc0, 16); xor_add4(acc0, 32);
    xor_add4(acc1, 16); xor_add4(acc1, 32);

    const float c0 = (float)n0;
    const float c1 = (float)n1;
    const float inv0 = c0 > 0.f ? rsqrtf(c0) : 0.f;
    const float inv1 = c1 > 0.f ? rsqrtf(c1) : 0.f;

    const int sid = __builtin_amdgcn_readfirstlane(scientist_ids[row]);
    const int pid = __builtin_amdgcn_readfirstlane(paper_ids[row]);
    const float4 sf = *(const float4*)(s_factors + (size_t)sid * EMBD + doff);
    const float4 pf = *(const float4*)(p_factors + (size_t)pid * EMBD + doff);

    float v = (sf.x + acc0.x * inv0 + acc1.x * inv1) * pf.x
            + (sf.y + acc0.y * inv0 + acc1.y * inv1) * pf.y
            + (sf.z + acc0.z * inv0 + acc1.z * inv1) * pf.z
            + (sf.w + acc0.w * inv0 + acc1.w * inv1) * pf.w;

    // reduce the 16 float4-slots (all 4 sub-groups now identical)
    v += __shfl_xor(v, 1, 64);
    v += __shfl_xor(v, 2, 64);
    v += __shfl_xor(v, 4, 64);
    v += __shfl_xor(v, 8, 64);

    if (lane == 0)
        out[row] = v + s_bias[sid] + p_bias[pid] + GLOBAL_MEAN;
}

extern "C" void kernel_launch(void* const* d_in, const int* in_sizes, int n_in,
                              void* d_out, int out_size, void* d_ws, size_t ws_size,
                              hipStream_t stream) {
    const int* scientist_ids = (const int*)d_in[0];
    const int* paper_ids     = (const int*)d_in[1];
    const int* sp_idx        = (const int*)d_in[2];
    const int* sp_seg        = (const int*)d_in[3];
    const int* sw_idx        = (const int*)d_in[4];
    const int* sw_seg        = (const int*)d_in[5];
    const float* s_factors   = (const float*)d_in[6];
    const float* p_factors   = (const float*)d_in[7];
    const float* s_bias      = (const float*)d_in[8];
    const float* p_bias      = (const float*)d_in[9];
    const float* imp_f       = (const float*)d_in[10];
    const float* imp_w       = (const float*)d_in[11];
    float* out = (float*)d_out;

    const int t_sp = in_sizes[2];
    const int t_sw = in_sizes[4];

    int* sp_start = (int*)d_ws;                    // BATCH+1 ints
    int* sw_start = sp_start + (BATCH + 1);        // BATCH+1 ints

    seg_bounds_kernel<<<(t_sp + 255) / 256, 256, 0, stream>>>(sp_seg, t_sp, sp_start);
    seg_bounds_kernel<<<(t_sw + 255) / 256, 256, 0, stream>>>(sw_seg, t_sw, sw_start);

    const int blocks = (BATCH * 64) / 256;   // one wave per row, 4 waves/block
    svdpp_fwd<<<blocks, 256, 0, stream>>>(
        scientist_ids, paper_ids,
        sp_idx, sp_start,
        sw_idx, sw_start,
        s_factors, p_factors, s_bias, p_bias,
        imp_f, imp_w, out);
}

// Round 4
// 52.288 us; speedup vs baseline: 2.3076x; 1.1831x over previous
//
#include <hip/hip_runtime.h>

#define BATCH 16384
#define EMBD 64
#define GLOBAL_MEAN 3.82f

// --- preprocessing: turn both sorted seg arrays into per-row [start,end) bounds ---
__global__ __launch_bounds__(256) void seg_bounds_fused(
    const int* __restrict__ sp_seg, int n_sp, int* __restrict__ sp_start,
    const int* __restrict__ sw_seg, int n_sw, int* __restrict__ sw_start)
{
    int i = blockIdx.x * blockDim.x + threadIdx.x;
    const int* seg; int n; int* start;
    if (i < n_sp) { seg = sp_seg; n = n_sp; start = sp_start; }
    else {
        i -= n_sp;
        if (i >= n_sw) return;
        seg = sw_seg; n = n_sw; start = sw_start;
    }
    int s = seg[i];
    int sprev = (i == 0) ? -1 : seg[i - 1];
    for (int r = sprev + 1; r <= s; ++r) start[r] = i;
    if (i == n - 1)
        for (int r = s + 1; r <= BATCH; ++r) start[r] = n;
}

__global__ __launch_bounds__(256) void svdpp_fwd(
    const int* __restrict__ scientist_ids,
    const int* __restrict__ paper_ids,
    const int* __restrict__ sp_idx, const int* __restrict__ sp_start,
    const int* __restrict__ sw_idx, const int* __restrict__ sw_start,
    const float* __restrict__ s_factors,
    const float* __restrict__ p_factors,
    const float* __restrict__ s_bias,
    const float* __restrict__ p_bias,
    const float* __restrict__ imp_f,
    const float* __restrict__ imp_w,
    float* __restrict__ out)
{
    const int wave = (blockIdx.x * blockDim.x + threadIdx.x) >> 6;
    const int lane = threadIdx.x & 63;
    if (wave >= BATCH) return;
    const int row  = wave;
    const int sub  = lane >> 4;        // which of 4 entries this lane helps load
    const int doff = (lane & 15) * 4;  // float4 slot: dims doff..doff+3

    const int s0 = __builtin_amdgcn_readfirstlane(sp_start[row]);
    const int e0 = __builtin_amdgcn_readfirstlane(sp_start[row + 1]);
    const int s1 = __builtin_amdgcn_readfirstlane(sw_start[row]);
    const int e1 = __builtin_amdgcn_readfirstlane(sw_start[row + 1]);
    const int n0 = e0 - s0;
    const int n1 = e1 - s1;

    // hoist the per-row embedding gathers so they're in flight during pooling
    const int sid = __builtin_amdgcn_readfirstlane(scientist_ids[row]);
    const int pid = __builtin_amdgcn_readfirstlane(paper_ids[row]);
    const float4 sf = *(const float4*)(s_factors + (size_t)sid * EMBD + doff);
    const float4 pf = *(const float4*)(p_factors + (size_t)pid * EMBD + doff);
    const float sb = s_bias[sid];
    const float pb = p_bias[pid];

    float4 acc0 = {0.f, 0.f, 0.f, 0.f};
    float4 acc1 = {0.f, 0.f, 0.f, 0.f};

    const int m = n0 > n1 ? n0 : n1;

    // chunked over both pools simultaneously: per chunk, prefetch up to 64
    // indices of each pool with ONE coalesced load each, distribute via shfl.
    // NOTE: inner loop trip count is WAVE-UNIFORM (tmax) so every __shfl
    // executes with all 64 lanes active — shfl from an exec-masked-off lane
    // is undefined and was the R3 bug. Accumulation is predicated instead.
    for (int c = 0; c < m; c += 64) {
        int i0 = s0 + c + lane;
        int i1 = s1 + c + lane;
        int a0 = i0 < e0 ? i0 : (e0 > s0 ? e0 - 1 : 0);
        int a1 = i1 < e1 ? i1 : (e1 > s1 ? e1 - 1 : 0);
        int my0 = sp_idx[a0];
        int my1 = sw_idx[a1];

        int r0 = n0 - c;  int lim0 = r0 < 64 ? r0 : 64;   // may be <=0
        int r1 = n1 - c;  int lim1 = r1 < 64 ? r1 : 64;
        int lim = lim0 > lim1 ? lim0 : lim1;              // 1..64
        int tmax = (lim + 3) >> 2;                        // uniform trip count

        #pragma unroll 4
        for (int t = 0; t < tmax; ++t) {
            int k = sub + 4 * t;                          // 0..63 always
            int id0 = __shfl(my0, k, 64);                 // all lanes active
            int id1 = __shfl(my1, k, 64);
            float4 v0 = *(const float4*)(imp_f + (size_t)id0 * EMBD + doff);
            float4 v1 = *(const float4*)(imp_w + (size_t)id1 * EMBD + doff);
            bool ok0 = k < lim0;
            bool ok1 = k < lim1;
            acc0.x += ok0 ? v0.x : 0.f;
            acc0.y += ok0 ? v0.y : 0.f;
            acc0.z += ok0 ? v0.z : 0.f;
            acc0.w += ok0 ? v0.w : 0.f;
            acc1.x += ok1 ? v1.x : 0.f;
            acc1.y += ok1 ? v1.y : 0.f;
            acc1.z += ok1 ? v1.z : 0.f;
            acc1.w += ok1 ? v1.w : 0.f;
        }
    }

    // combine the 4 sub-groups: after xor(16)+xor(32) every lane holds the
    // full pooled sum for its 4 dims
    acc0.x += __shfl_xor(acc0.x, 16, 64); acc0.x += __shfl_xor(acc0.x, 32, 64);
    acc0.y += __shfl_xor(acc0.y, 16, 64); acc0.y += __shfl_xor(acc0.y, 32, 64);
    acc0.z += __shfl_xor(acc0.z, 16, 64); acc0.z += __shfl_xor(acc0.z, 32, 64);
    acc0.w += __shfl_xor(acc0.w, 16, 64); acc0.w += __shfl_xor(acc0.w, 32, 64);
    acc1.x += __shfl_xor(acc1.x, 16, 64); acc1.x += __shfl_xor(acc1.x, 32, 64);
    acc1.y += __shfl_xor(acc1.y, 16, 64); acc1.y += __shfl_xor(acc1.y, 32, 64);
    acc1.z += __shfl_xor(acc1.z, 16, 64); acc1.z += __shfl_xor(acc1.z, 32, 64);
    acc1.w += __shfl_xor(acc1.w, 16, 64); acc1.w += __shfl_xor(acc1.w, 32, 64);

    const float inv0 = n0 > 0 ? rsqrtf((float)n0) : 0.f;
    const float inv1 = n1 > 0 ? rsqrtf((float)n1) : 0.f;

    float v = (sf.x + acc0.x * inv0 + acc1.x * inv1) * pf.x
            + (sf.y + acc0.y * inv0 + acc1.y * inv1) * pf.y
            + (sf.z + acc0.z * inv0 + acc1.z * inv1) * pf.z
            + (sf.w + acc0.w * inv0 + acc1.w * inv1) * pf.w;

    // reduce across the 16 float4-slots
    v += __shfl_xor(v, 1, 64);
    v += __shfl_xor(v, 2, 64);
    v += __shfl_xor(v, 4, 64);
    v += __shfl_xor(v, 8, 64);

    if (lane == 0)
        out[row] = v + sb + pb + GLOBAL_MEAN;
}

extern "C" void kernel_launch(void* const* d_in, const int* in_sizes, int n_in,
                              void* d_out, int out_size, void* d_ws, size_t ws_size,
                              hipStream_t stream) {
    const int* scientist_ids = (const int*)d_in[0];
    const int* paper_ids     = (const int*)d_in[1];
    const int* sp_idx        = (const int*)d_in[2];
    const int* sp_seg        = (const int*)d_in[3];
    const int* sw_idx        = (const int*)d_in[4];
    const int* sw_seg        = (const int*)d_in[5];
    const float* s_factors   = (const float*)d_in[6];
    const float* p_factors   = (const float*)d_in[7];
    const float* s_bias      = (const float*)d_in[8];
    const float* p_bias      = (const float*)d_in[9];
    const float* imp_f       = (const float*)d_in[10];
    const float* imp_w       = (const float*)d_in[11];
    float* out = (float*)d_out;

    const int t_sp = in_sizes[2];
    const int t_sw = in_sizes[4];

    int* sp_start = (int*)d_ws;                    // BATCH+1 ints
    int* sw_start = sp_start + (BATCH + 1);        // BATCH+1 ints

    seg_bounds_fused<<<(t_sp + t_sw + 255) / 256, 256, 0, stream>>>(
        sp_seg, t_sp, sp_start, sw_seg, t_sw, sw_start);

    const int blocks = (BATCH * 64) / 256;   // one wave per row, 4 waves/block
    svdpp_fwd<<<blocks, 256, 0, stream>>>(
        scientist_ids, paper_ids,
        sp_idx, sp_start,
        sw_idx, sw_start,
        s_factors, p_factors, s_bias, p_bias,
        imp_f, imp_w, out);
}

// Round 5
// 51.966 us; speedup vs baseline: 2.3220x; 1.0062x over previous
//
#include <hip/hip_runtime.h>

#define BATCH 16384
#define EMBD 64
#define GLOBAL_MEAN 3.82f

// --- preprocessing: turn both sorted seg arrays into per-row [start,end) bounds ---
__global__ __launch_bounds__(256) void seg_bounds_fused(
    const int* __restrict__ sp_seg, int n_sp, int* __restrict__ sp_start,
    const int* __restrict__ sw_seg, int n_sw, int* __restrict__ sw_start)
{
    int i = blockIdx.x * blockDim.x + threadIdx.x;
    const int* seg; int n; int* start;
    if (i < n_sp) { seg = sp_seg; n = n_sp; start = sp_start; }
    else {
        i -= n_sp;
        if (i >= n_sw) return;
        seg = sw_seg; n = n_sw; start = sw_start;
    }
    int s = seg[i];
    int sprev = (i == 0) ? -1 : seg[i - 1];
    for (int r = sprev + 1; r <= s; ++r) start[r] = i;
    if (i == n - 1)
        for (int r = s + 1; r <= BATCH; ++r) start[r] = n;
}

__global__ __launch_bounds__(256) void svdpp_fwd(
    const int* __restrict__ scientist_ids,
    const int* __restrict__ paper_ids,
    const int* __restrict__ sp_idx, const int* __restrict__ sp_start,
    const int* __restrict__ sw_idx, const int* __restrict__ sw_start,
    const float* __restrict__ s_factors,
    const float* __restrict__ p_factors,
    const float* __restrict__ s_bias,
    const float* __restrict__ p_bias,
    const float* __restrict__ imp_f,
    const float* __restrict__ imp_w,
    float* __restrict__ out)
{
    const int wave = (blockIdx.x * blockDim.x + threadIdx.x) >> 6;
    const int lane = threadIdx.x & 63;
    if (wave >= BATCH) return;
    const int row  = wave;
    const int sub  = lane >> 4;        // which of 4 entries this lane helps load
    const int doff = (lane & 15) * 4;  // float4 slot: dims doff..doff+3

    const int s0 = __builtin_amdgcn_readfirstlane(sp_start[row]);
    const int e0 = __builtin_amdgcn_readfirstlane(sp_start[row + 1]);
    const int s1 = __builtin_amdgcn_readfirstlane(sw_start[row]);
    const int e1 = __builtin_amdgcn_readfirstlane(sw_start[row + 1]);
    const int n0 = e0 - s0;
    const int n1 = e1 - s1;

    // hoist per-row embedding gathers so they're in flight during pooling
    const int sid = __builtin_amdgcn_readfirstlane(scientist_ids[row]);
    const int pid = __builtin_amdgcn_readfirstlane(paper_ids[row]);
    const float4 sf = *(const float4*)(s_factors + (size_t)sid * EMBD + doff);
    const float4 pf = *(const float4*)(p_factors + (size_t)pid * EMBD + doff);
    const float sb = s_bias[sid];
    const float pb = p_bias[pid];

    float4 acc0 = {0.f, 0.f, 0.f, 0.f};
    float4 acc1 = {0.f, 0.f, 0.f, 0.f};

    const int m = n0 > n1 ? n0 : n1;

    // Per 64-entry chunk: ONE coalesced idx load per pool, distribute via
    // bpermute (all-lanes-active: trip counts are wave-uniform, shfl k<=63),
    // then explicit 8-deep register-array batches -> 16 independent float4
    // gathers in flight before any accumulate (MLP is the whole game here).
    for (int c = 0; c < m; c += 64) {
        int i0 = s0 + c + lane;
        int i1 = s1 + c + lane;
        int a0 = i0 < e0 ? i0 : (e0 > s0 ? e0 - 1 : 0);
        int a1 = i1 < e1 ? i1 : (e1 > s1 ? e1 - 1 : 0);
        int my0 = sp_idx[a0];
        int my1 = sw_idx[a1];

        int r0 = n0 - c;  int lim0 = r0 < 64 ? r0 : 64;   // may be <=0
        int r1 = n1 - c;  int lim1 = r1 < 64 ? r1 : 64;
        int lim = lim0 > lim1 ? lim0 : lim1;              // 1..64
        int jmax  = (lim  + 3) >> 2;                      // uniform, 1..16
        int jm0   = (lim0 + 3) >> 2; if (jm0 < 1) jm0 = 1;  // per-pool clamp tops
        int jm1   = (lim1 + 3) >> 2; if (jm1 < 1) jm1 = 1;

        for (int step = 0; step < jmax; step += 8) {
            int id0[8], id1[8];
            #pragma unroll
            for (int u = 0; u < 8; ++u) {
                int j  = step + u;
                int j0 = j < jm0 ? j : jm0 - 1;           // clamped: shfl k<=63
                int j1 = j < jm1 ? j : jm1 - 1;
                id0[u] = __shfl(my0, sub + 4 * j0, 64);
                id1[u] = __shfl(my1, sub + 4 * j1, 64);
            }
            float4 v0[8], v1[8];
            #pragma unroll
            for (int u = 0; u < 8; ++u) {
                v0[u] = *(const float4*)(imp_f + (size_t)id0[u] * EMBD + doff);
                v1[u] = *(const float4*)(imp_w + (size_t)id1[u] * EMBD + doff);
            }
            #pragma unroll
            for (int u = 0; u < 8; ++u) {
                int k = sub + 4 * (step + u);             // unclamped entry id
                bool ok0 = k < lim0;
                bool ok1 = k < lim1;
                acc0.x += ok0 ? v0[u].x : 0.f;
                acc0.y += ok0 ? v0[u].y : 0.f;
                acc0.z += ok0 ? v0[u].z : 0.f;
                acc0.w += ok0 ? v0[u].w : 0.f;
                acc1.x += ok1 ? v1[u].x : 0.f;
                acc1.y += ok1 ? v1[u].y : 0.f;
                acc1.z += ok1 ? v1[u].z : 0.f;
                acc1.w += ok1 ? v1[u].w : 0.f;
            }
        }
    }

    // combine the 4 sub-groups: after xor(16)+xor(32) every lane holds the
    // full pooled sum for its 4 dims
    acc0.x += __shfl_xor(acc0.x, 16, 64); acc0.x += __shfl_xor(acc0.x, 32, 64);
    acc0.y += __shfl_xor(acc0.y, 16, 64); acc0.y += __shfl_xor(acc0.y, 32, 64);
    acc0.z += __shfl_xor(acc0.z, 16, 64); acc0.z += __shfl_xor(acc0.z, 32, 64);
    acc0.w += __shfl_xor(acc0.w, 16, 64); acc0.w += __shfl_xor(acc0.w, 32, 64);
    acc1.x += __shfl_xor(acc1.x, 16, 64); acc1.x += __shfl_xor(acc1.x, 32, 64);
    acc1.y += __shfl_xor(acc1.y, 16, 64); acc1.y += __shfl_xor(acc1.y, 32, 64);
    acc1.z += __shfl_xor(acc1.z, 16, 64); acc1.z += __shfl_xor(acc1.z, 32, 64);
    acc1.w += __shfl_xor(acc1.w, 16, 64); acc1.w += __shfl_xor(acc1.w, 32, 64);

    const float inv0 = n0 > 0 ? rsqrtf((float)n0) : 0.f;
    const float inv1 = n1 > 0 ? rsqrtf((float)n1) : 0.f;

    float v = (sf.x + acc0.x * inv0 + acc1.x * inv1) * pf.x
            + (sf.y + acc0.y * inv0 + acc1.y * inv1) * pf.y
            + (sf.z + acc0.z * inv0 + acc1.z * inv1) * pf.z
            + (sf.w + acc0.w * inv0 + acc1.w * inv1) * pf.w;

    // reduce across the 16 float4-slots
    v += __shfl_xor(v, 1, 64);
    v += __shfl_xor(v, 2, 64);
    v += __shfl_xor(v, 4, 64);
    v += __shfl_xor(v, 8, 64);

    if (lane == 0)
        out[row] = v + sb + pb + GLOBAL_MEAN;
}

extern "C" void kernel_launch(void* const* d_in, const int* in_sizes, int n_in,
                              void* d_out, int out_size, void* d_ws, size_t ws_size,
                              hipStream_t stream) {
    const int* scientist_ids = (const int*)d_in[0];
    const int* paper_ids     = (const int*)d_in[1];
    const int* sp_idx        = (const int*)d_in[2];
    const int* sp_seg        = (const int*)d_in[3];
    const int* sw_idx        = (const int*)d_in[4];
    const int* sw_seg        = (const int*)d_in[5];
    const float* s_factors   = (const float*)d_in[6];
    const float* p_factors   = (const float*)d_in[7];
    const float* s_bias      = (const float*)d_in[8];
    const float* p_bias      = (const float*)d_in[9];
    const float* imp_f       = (const float*)d_in[10];
    const float* imp_w       = (const float*)d_in[11];
    float* out = (float*)d_out;

    const int t_sp = in_sizes[2];
    const int t_sw = in_sizes[4];

    int* sp_start = (int*)d_ws;                    // BATCH+1 ints
    int* sw_start = sp_start + (BATCH + 1);        // BATCH+1 ints

    seg_bounds_fused<<<(t_sp + t_sw + 255) / 256, 256, 0, stream>>>(
        sp_seg, t_sp, sp_start, sw_seg, t_sw, sw_start);

    const int blocks = (BATCH * 64) / 256;   // one wave per row, 4 waves/block
    svdpp_fwd<<<blocks, 256, 0, stream>>>(
        scientist_ids, paper_ids,
        sp_idx, sp_start,
        sw_idx, sw_start,
        s_factors, p_factors, s_bias, p_bias,
        imp_f, imp_w, out);
}

// Round 6
// 50.743 us; speedup vs baseline: 2.3779x; 1.0241x over previous
//
#include <hip/hip_runtime.h>

#define BATCH 16384
#define EMBD 64
#define GLOBAL_MEAN 3.82f

// --- preprocessing: seg bounds for both pools + zero dummy row in ws ---
__global__ __launch_bounds__(256) void seg_bounds_fused(
    const int* __restrict__ sp_seg, int n_sp, int* __restrict__ sp_start,
    const int* __restrict__ sw_seg, int n_sw, int* __restrict__ sw_start,
    float* __restrict__ zrow)
{
    int gi = blockIdx.x * blockDim.x + threadIdx.x;
    if (gi < EMBD) zrow[gi] = 0.0f;          // 256B zero row for clamped gathers
    int i = gi;
    const int* seg; int n; int* start;
    if (i < n_sp) { seg = sp_seg; n = n_sp; start = sp_start; }
    else {
        i -= n_sp;
        if (i >= n_sw) return;
        seg = sw_seg; n = n_sw; start = sw_start;
    }
    int s = seg[i];
    int sprev = (i == 0) ? -1 : seg[i - 1];
    for (int r = sprev + 1; r <= s; ++r) start[r] = i;
    if (i == n - 1)
        for (int r = s + 1; r <= BATCH; ++r) start[r] = n;
}

// one wave per batch row; VGPR<=64 (8 waves/SIMD) AND 8-deep gather batches.
__global__ __launch_bounds__(256, 8) void svdpp_fwd(
    const int* __restrict__ scientist_ids,
    const int* __restrict__ paper_ids,
    const int* __restrict__ sp_idx, const int* __restrict__ sp_start,
    const int* __restrict__ sw_idx, const int* __restrict__ sw_start,
    const float* __restrict__ s_factors,
    const float* __restrict__ p_factors,
    const float* __restrict__ s_bias,
    const float* __restrict__ p_bias,
    const float* __restrict__ imp_f,
    const float* __restrict__ imp_w,
    const float* __restrict__ zrow,
    float* __restrict__ out)
{
    const int wave = (blockIdx.x * blockDim.x + threadIdx.x) >> 6;
    const int lane = threadIdx.x & 63;
    if (wave >= BATCH) return;
    const int row  = wave;
    const int sub  = lane >> 4;        // which of 4 entries this lane helps load
    const int doff = (lane & 15) * 4;  // float4 slot: dims doff..doff+3

    const int s0 = __builtin_amdgcn_readfirstlane(sp_start[row]);
    const int e0 = __builtin_amdgcn_readfirstlane(sp_start[row + 1]);
    const int s1 = __builtin_amdgcn_readfirstlane(sw_start[row]);
    const int e1 = __builtin_amdgcn_readfirstlane(sw_start[row + 1]);
    const int n0 = e0 - s0;
    const int n1 = e1 - s1;

    // hoist per-row embedding gathers so they're in flight during pooling
    const int sid = __builtin_amdgcn_readfirstlane(scientist_ids[row]);
    const int pid = __builtin_amdgcn_readfirstlane(paper_ids[row]);
    const float4 sf = *(const float4*)(s_factors + (size_t)sid * EMBD + doff);
    const float4 pf = *(const float4*)(p_factors + (size_t)pid * EMBD + doff);
    const float sb = s_bias[sid];
    const float pb = p_bias[pid];

    float4 acc0 = {0.f, 0.f, 0.f, 0.f};
    float4 acc1 = {0.f, 0.f, 0.f, 0.f};

    const int m = n0 > n1 ? n0 : n1;

    // Per 64-entry chunk and per pool: ONE coalesced idx load, distribute via
    // shfl (trip counts wave-uniform -> all lanes active at every shfl), then
    // 8 independent float4 gathers in flight before any accumulate.
    // Out-of-range entries gather the zero row (unconditional +0.0 is exact),
    // so no predication registers and minimal VALU in the hot loop.
    for (int c = 0; c < m; c += 64) {
        // ---- pool 0 (implicit_factors) ----
        int r0 = n0 - c;
        if (r0 > 0) {
            int lim0 = r0 < 64 ? r0 : 64;
            int i0 = s0 + c + lane;
            int a0 = i0 < e0 ? i0 : e0 - 1;
            int my0 = sp_idx[a0];
            int jm = (lim0 + 3) >> 2;                 // 1..16
            for (int step = 0; step < jm; step += 8) {
                float4 v[8];
                #pragma unroll
                for (int u = 0; u < 8; ++u) {
                    int k = sub + 4 * (step + u);     // <= 63 always
                    int idx = __shfl(my0, k, 64);
                    const float* base = (k < lim0) ? (imp_f + (size_t)idx * EMBD) : zrow;
                    v[u] = *(const float4*)(base + doff);
                }
                #pragma unroll
                for (int u = 0; u < 8; ++u) {
                    acc0.x += v[u].x; acc0.y += v[u].y;
                    acc0.z += v[u].z; acc0.w += v[u].w;
                }
            }
        }
        // ---- pool 1 (implicit_wishlist) ----
        int r1 = n1 - c;
        if (r1 > 0) {
            int lim1 = r1 < 64 ? r1 : 64;
            int i1 = s1 + c + lane;
            int a1 = i1 < e1 ? i1 : e1 - 1;
            int my1 = sw_idx[a1];
            int jm = (lim1 + 3) >> 2;
            for (int step = 0; step < jm; step += 8) {
                float4 v[8];
                #pragma unroll
                for (int u = 0; u < 8; ++u) {
                    int k = sub + 4 * (step + u);
                    int idx = __shfl(my1, k, 64);
                    const float* base = (k < lim1) ? (imp_w + (size_t)idx * EMBD) : zrow;
                    v[u] = *(const float4*)(base + doff);
                }
                #pragma unroll
                for (int u = 0; u < 8; ++u) {
                    acc1.x += v[u].x; acc1.y += v[u].y;
                    acc1.z += v[u].z; acc1.w += v[u].w;
                }
            }
        }
    }

    // combine the 4 sub-groups: after xor(16)+xor(32) every lane holds the
    // full pooled sum for its 4 dims
    acc0.x += __shfl_xor(acc0.x, 16, 64); acc0.x += __shfl_xor(acc0.x, 32, 64);
    acc0.y += __shfl_xor(acc0.y, 16, 64); acc0.y += __shfl_xor(acc0.y, 32, 64);
    acc0.z += __shfl_xor(acc0.z, 16, 64); acc0.z += __shfl_xor(acc0.z, 32, 64);
    acc0.w += __shfl_xor(acc0.w, 16, 64); acc0.w += __shfl_xor(acc0.w, 32, 64);
    acc1.x += __shfl_xor(acc1.x, 16, 64); acc1.x += __shfl_xor(acc1.x, 32, 64);
    acc1.y += __shfl_xor(acc1.y, 16, 64); acc1.y += __shfl_xor(acc1.y, 32, 64);
    acc1.z += __shfl_xor(acc1.z, 16, 64); acc1.z += __shfl_xor(acc1.z, 32, 64);
    acc1.w += __shfl_xor(acc1.w, 16, 64); acc1.w += __shfl_xor(acc1.w, 32, 64);

    const float inv0 = n0 > 0 ? rsqrtf((float)n0) : 0.f;
    const float inv1 = n1 > 0 ? rsqrtf((float)n1) : 0.f;

    float v = (sf.x + acc0.x * inv0 + acc1.x * inv1) * pf.x
            + (sf.y + acc0.y * inv0 + acc1.y * inv1) * pf.y
            + (sf.z + acc0.z * inv0 + acc1.z * inv1) * pf.z
            + (sf.w + acc0.w * inv0 + acc1.w * inv1) * pf.w;

    // reduce across the 16 float4-slots
    v += __shfl_xor(v, 1, 64);
    v += __shfl_xor(v, 2, 64);
    v += __shfl_xor(v, 4, 64);
    v += __shfl_xor(v, 8, 64);

    if (lane == 0)
        out[row] = v + sb + pb + GLOBAL_MEAN;
}

extern "C" void kernel_launch(void* const* d_in, const int* in_sizes, int n_in,
                              void* d_out, int out_size, void* d_ws, size_t ws_size,
                              hipStream_t stream) {
    const int* scientist_ids = (const int*)d_in[0];
    const int* paper_ids     = (const int*)d_in[1];
    const int* sp_idx        = (const int*)d_in[2];
    const int* sp_seg        = (const int*)d_in[3];
    const int* sw_idx        = (const int*)d_in[4];
    const int* sw_seg        = (const int*)d_in[5];
    const float* s_factors   = (const float*)d_in[6];
    const float* p_factors   = (const float*)d_in[7];
    const float* s_bias      = (const float*)d_in[8];
    const float* p_bias      = (const float*)d_in[9];
    const float* imp_f       = (const float*)d_in[10];
    const float* imp_w       = (const float*)d_in[11];
    float* out = (float*)d_out;

    const int t_sp = in_sizes[2];
    const int t_sw = in_sizes[4];

    // ws layout: [zero row: 64 floats][sp_start: B+1 ints][sw_start: B+1 ints]
    float* zrow   = (float*)d_ws;
    int* sp_start = (int*)(zrow + EMBD);
    int* sw_start = sp_start + (BATCH + 1);

    seg_bounds_fused<<<(t_sp + t_sw + 255) / 256, 256, 0, stream>>>(
        sp_seg, t_sp, sp_start, sw_seg, t_sw, sw_start, zrow);

    const int blocks = (BATCH * 64) / 256;   // one wave per row, 4 waves/block
    svdpp_fwd<<<blocks, 256, 0, stream>>>(
        scientist_ids, paper_ids,
        sp_idx, sp_start,
        sw_idx, sw_start,
        s_factors, p_factors, s_bias, p_bias,
        imp_f, imp_w, zrow, out);
}

// Round 7
// 39.039 us; speedup vs baseline: 3.0908x; 1.2998x over previous
//
#include <hip/hip_runtime.h>

#define BATCH 16384
#define EMBD 64
#define GLOBAL_MEAN 3.82f

typedef unsigned short u16;

__device__ __forceinline__ u16 f32_to_bf16_rne(float f) {
    unsigned int u = __float_as_uint(f);
    unsigned int lsb = (u >> 16) & 1u;
    u += 0x7fffu + lsb;
    return (u16)(u >> 16);
}
__device__ __forceinline__ float bf16_to_f32(u16 h) {
    return __uint_as_float(((unsigned int)h) << 16);
}

// --- preprocessing A: seg bounds for both pools + f32 zero row ---
__global__ __launch_bounds__(256) void seg_bounds_fused(
    const int* __restrict__ sp_seg, int n_sp, int* __restrict__ sp_start,
    const int* __restrict__ sw_seg, int n_sw, int* __restrict__ sw_start,
    float* __restrict__ zrowf)
{
    int gi = blockIdx.x * blockDim.x + threadIdx.x;
    if (gi < EMBD) zrowf[gi] = 0.0f;
    int i = gi;
    const int* seg; int n; int* start;
    if (i < n_sp) { seg = sp_seg; n = n_sp; start = sp_start; }
    else {
        i -= n_sp;
        if (i >= n_sw) return;
        seg = sw_seg; n = n_sw; start = sw_start;
    }
    int s = seg[i];
    int sprev = (i == 0) ? -1 : seg[i - 1];
    for (int r = sprev + 1; r <= s; ++r) start[r] = i;
    if (i == n - 1)
        for (int r = s + 1; r <= BATCH; ++r) start[r] = n;
}

// --- preprocessing B: f32 tables -> bf16 tables (+ bf16 zero row) ---
__global__ __launch_bounds__(256) void convert_bf16(
    const float* __restrict__ tf, const float* __restrict__ tw,
    u16* __restrict__ f16, u16* __restrict__ w16,
    int elems_per_table, u16* __restrict__ zrow16)
{
    int tid = blockIdx.x * blockDim.x + threadIdx.x;
    if (tid < EMBD) zrow16[tid] = 0;
    int q = elems_per_table >> 2;          // float4 chunks per table
    const float* src; u16* dst; int i = tid;
    if (i < q) { src = tf; dst = f16; }
    else {
        i -= q;
        if (i >= q) return;
        src = tw; dst = w16;
    }
    float4 v = *(const float4*)(src + (size_t)i * 4);
    ushort4 o;
    o.x = f32_to_bf16_rne(v.x);
    o.y = f32_to_bf16_rne(v.y);
    o.z = f32_to_bf16_rne(v.z);
    o.w = f32_to_bf16_rne(v.w);
    *(ushort4*)(dst + (size_t)i * 4) = o;
}

// ================= main kernel, bf16 gather path =================
__global__ __launch_bounds__(256, 8) void svdpp_fwd_bf16(
    const int* __restrict__ scientist_ids,
    const int* __restrict__ paper_ids,
    const int* __restrict__ sp_idx, const int* __restrict__ sp_start,
    const int* __restrict__ sw_idx, const int* __restrict__ sw_start,
    const float* __restrict__ s_factors,
    const float* __restrict__ p_factors,
    const float* __restrict__ s_bias,
    const float* __restrict__ p_bias,
    const u16* __restrict__ f16,      // bf16 implicit_factors
    const u16* __restrict__ w16,      // bf16 implicit_wishlist
    const u16* __restrict__ zrow16,
    float* __restrict__ out)
{
    const int wave = (blockIdx.x * blockDim.x + threadIdx.x) >> 6;
    const int lane = threadIdx.x & 63;
    if (wave >= BATCH) return;
    const int row  = wave;
    const int sub  = lane >> 4;        // which of 4 entries this lane helps load
    const int doff = (lane & 15) * 4;  // element offset of this lane's 4 dims

    const int s0 = __builtin_amdgcn_readfirstlane(sp_start[row]);
    const int e0 = __builtin_amdgcn_readfirstlane(sp_start[row + 1]);
    const int s1 = __builtin_amdgcn_readfirstlane(sw_start[row]);
    const int e1 = __builtin_amdgcn_readfirstlane(sw_start[row + 1]);
    const int n0 = e0 - s0;
    const int n1 = e1 - s1;

    const int sid = __builtin_amdgcn_readfirstlane(scientist_ids[row]);
    const int pid = __builtin_amdgcn_readfirstlane(paper_ids[row]);
    const float4 sf = *(const float4*)(s_factors + (size_t)sid * EMBD + doff);
    const float4 pf = *(const float4*)(p_factors + (size_t)pid * EMBD + doff);
    const float sb = s_bias[sid];
    const float pb = p_bias[pid];

    float4 acc0 = {0.f, 0.f, 0.f, 0.f};
    float4 acc1 = {0.f, 0.f, 0.f, 0.f};

    const int m = n0 > n1 ? n0 : n1;

    for (int c = 0; c < m; c += 64) {
        // ---- pool 0 (implicit_factors, bf16) ----
        int r0 = n0 - c;
        if (r0 > 0) {
            int lim0 = r0 < 64 ? r0 : 64;
            int i0 = s0 + c + lane;
            int a0 = i0 < e0 ? i0 : e0 - 1;
            int my0 = sp_idx[a0];
            int jm = (lim0 + 3) >> 2;
            for (int step = 0; step < jm; step += 8) {
                ushort4 v[8];
                #pragma unroll
                for (int u = 0; u < 8; ++u) {
                    int k = sub + 4 * (step + u);     // <= 63 always
                    int idx = __shfl(my0, k, 64);     // all lanes active
                    const u16* base = (k < lim0) ? (f16 + (size_t)idx * EMBD) : zrow16;
                    v[u] = *(const ushort4*)(base + doff);
                }
                #pragma unroll
                for (int u = 0; u < 8; ++u) {
                    acc0.x += bf16_to_f32(v[u].x);
                    acc0.y += bf16_to_f32(v[u].y);
                    acc0.z += bf16_to_f32(v[u].z);
                    acc0.w += bf16_to_f32(v[u].w);
                }
            }
        }
        // ---- pool 1 (implicit_wishlist, bf16) ----
        int r1 = n1 - c;
        if (r1 > 0) {
            int lim1 = r1 < 64 ? r1 : 64;
            int i1 = s1 + c + lane;
            int a1 = i1 < e1 ? i1 : e1 - 1;
            int my1 = sw_idx[a1];
            int jm = (lim1 + 3) >> 2;
            for (int step = 0; step < jm; step += 8) {
                ushort4 v[8];
                #pragma unroll
                for (int u = 0; u < 8; ++u) {
                    int k = sub + 4 * (step + u);
                    int idx = __shfl(my1, k, 64);
                    const u16* base = (k < lim1) ? (w16 + (size_t)idx * EMBD) : zrow16;
                    v[u] = *(const ushort4*)(base + doff);
                }
                #pragma unroll
                for (int u = 0; u < 8; ++u) {
                    acc1.x += bf16_to_f32(v[u].x);
                    acc1.y += bf16_to_f32(v[u].y);
                    acc1.z += bf16_to_f32(v[u].z);
                    acc1.w += bf16_to_f32(v[u].w);
                }
            }
        }
    }

    acc0.x += __shfl_xor(acc0.x, 16, 64); acc0.x += __shfl_xor(acc0.x, 32, 64);
    acc0.y += __shfl_xor(acc0.y, 16, 64); acc0.y += __shfl_xor(acc0.y, 32, 64);
    acc0.z += __shfl_xor(acc0.z, 16, 64); acc0.z += __shfl_xor(acc0.z, 32, 64);
    acc0.w += __shfl_xor(acc0.w, 16, 64); acc0.w += __shfl_xor(acc0.w, 32, 64);
    acc1.x += __shfl_xor(acc1.x, 16, 64); acc1.x += __shfl_xor(acc1.x, 32, 64);
    acc1.y += __shfl_xor(acc1.y, 16, 64); acc1.y += __shfl_xor(acc1.y, 32, 64);
    acc1.z += __shfl_xor(acc1.z, 16, 64); acc1.z += __shfl_xor(acc1.z, 32, 64);
    acc1.w += __shfl_xor(acc1.w, 16, 64); acc1.w += __shfl_xor(acc1.w, 32, 64);

    const float inv0 = n0 > 0 ? rsqrtf((float)n0) : 0.f;
    const float inv1 = n1 > 0 ? rsqrtf((float)n1) : 0.f;

    float v = (sf.x + acc0.x * inv0 + acc1.x * inv1) * pf.x
            + (sf.y + acc0.y * inv0 + acc1.y * inv1) * pf.y
            + (sf.z + acc0.z * inv0 + acc1.z * inv1) * pf.z
            + (sf.w + acc0.w * inv0 + acc1.w * inv1) * pf.w;

    v += __shfl_xor(v, 1, 64);
    v += __shfl_xor(v, 2, 64);
    v += __shfl_xor(v, 4, 64);
    v += __shfl_xor(v, 8, 64);

    if (lane == 0)
        out[row] = v + sb + pb + GLOBAL_MEAN;
}

// ================= fallback: f32 gather path (R6) =================
__global__ __launch_bounds__(256, 8) void svdpp_fwd_f32(
    const int* __restrict__ scientist_ids,
    const int* __restrict__ paper_ids,
    const int* __restrict__ sp_idx, const int* __restrict__ sp_start,
    const int* __restrict__ sw_idx, const int* __restrict__ sw_start,
    const float* __restrict__ s_factors,
    const float* __restrict__ p_factors,
    const float* __restrict__ s_bias,
    const float* __restrict__ p_bias,
    const float* __restrict__ imp_f,
    const float* __restrict__ imp_w,
    const float* __restrict__ zrow,
    float* __restrict__ out)
{
    const int wave = (blockIdx.x * blockDim.x + threadIdx.x) >> 6;
    const int lane = threadIdx.x & 63;
    if (wave >= BATCH) return;
    const int row  = wave;
    const int sub  = lane >> 4;
    const int doff = (lane & 15) * 4;

    const int s0 = __builtin_amdgcn_readfirstlane(sp_start[row]);
    const int e0 = __builtin_amdgcn_readfirstlane(sp_start[row + 1]);
    const int s1 = __builtin_amdgcn_readfirstlane(sw_start[row]);
    const int e1 = __builtin_amdgcn_readfirstlane(sw_start[row + 1]);
    const int n0 = e0 - s0;
    const int n1 = e1 - s1;

    const int sid = __builtin_amdgcn_readfirstlane(scientist_ids[row]);
    const int pid = __builtin_amdgcn_readfirstlane(paper_ids[row]);
    const float4 sf = *(const float4*)(s_factors + (size_t)sid * EMBD + doff);
    const float4 pf = *(const float4*)(p_factors + (size_t)pid * EMBD + doff);
    const float sb = s_bias[sid];
    const float pb = p_bias[pid];

    float4 acc0 = {0.f, 0.f, 0.f, 0.f};
    float4 acc1 = {0.f, 0.f, 0.f, 0.f};
    const int m = n0 > n1 ? n0 : n1;

    for (int c = 0; c < m; c += 64) {
        int r0 = n0 - c;
        if (r0 > 0) {
            int lim0 = r0 < 64 ? r0 : 64;
            int i0 = s0 + c + lane;
            int a0 = i0 < e0 ? i0 : e0 - 1;
            int my0 = sp_idx[a0];
            int jm = (lim0 + 3) >> 2;
            for (int step = 0; step < jm; step += 8) {
                float4 v[8];
                #pragma unroll
                for (int u = 0; u < 8; ++u) {
                    int k = sub + 4 * (step + u);
                    int idx = __shfl(my0, k, 64);
                    const float* base = (k < lim0) ? (imp_f + (size_t)idx * EMBD) : zrow;
                    v[u] = *(const float4*)(base + doff);
                }
                #pragma unroll
                for (int u = 0; u < 8; ++u) {
                    acc0.x += v[u].x; acc0.y += v[u].y;
                    acc0.z += v[u].z; acc0.w += v[u].w;
                }
            }
        }
        int r1 = n1 - c;
        if (r1 > 0) {
            int lim1 = r1 < 64 ? r1 : 64;
            int i1 = s1 + c + lane;
            int a1 = i1 < e1 ? i1 : e1 - 1;
            int my1 = sw_idx[a1];
            int jm = (lim1 + 3) >> 2;
            for (int step = 0; step < jm; step += 8) {
                float4 v[8];
                #pragma unroll
                for (int u = 0; u < 8; ++u) {
                    int k = sub + 4 * (step + u);
                    int idx = __shfl(my1, k, 64);
                    const float* base = (k < lim1) ? (imp_w + (size_t)idx * EMBD) : zrow;
                    v[u] = *(const float4*)(base + doff);
                }
                #pragma unroll
                for (int u = 0; u < 8; ++u) {
                    acc1.x += v[u].x; acc1.y += v[u].y;
                    acc1.z += v[u].z; acc1.w += v[u].w;
                }
            }
        }
    }

    acc0.x += __shfl_xor(acc0.x, 16, 64); acc0.x += __shfl_xor(acc0.x, 32, 64);
    acc0.y += __shfl_xor(acc0.y, 16, 64); acc0.y += __shfl_xor(acc0.y, 32, 64);
    acc0.z += __shfl_xor(acc0.z, 16, 64); acc0.z += __shfl_xor(acc0.z, 32, 64);
    acc0.w += __shfl_xor(acc0.w, 16, 64); acc0.w += __shfl_xor(acc0.w, 32, 64);
    acc1.x += __shfl_xor(acc1.x, 16, 64); acc1.x += __shfl_xor(acc1.x, 32, 64);
    acc1.y += __shfl_xor(acc1.y, 16, 64); acc1.y += __shfl_xor(acc1.y, 32, 64);
    acc1.z += __shfl_xor(acc1.z, 16, 64); acc1.z += __shfl_xor(acc1.z, 32, 64);
    acc1.w += __shfl_xor(acc1.w, 16, 64); acc1.w += __shfl_xor(acc1.w, 32, 64);

    const float inv0 = n0 > 0 ? rsqrtf((float)n0) : 0.f;
    const float inv1 = n1 > 0 ? rsqrtf((float)n1) : 0.f;

    float v = (sf.x + acc0.x * inv0 + acc1.x * inv1) * pf.x
            + (sf.y + acc0.y * inv0 + acc1.y * inv1) * pf.y
            + (sf.z + acc0.z * inv0 + acc1.z * inv1) * pf.z
            + (sf.w + acc0.w * inv0 + acc1.w * inv1) * pf.w;

    v += __shfl_xor(v, 1, 64);
    v += __shfl_xor(v, 2, 64);
    v += __shfl_xor(v, 4, 64);
    v += __shfl_xor(v, 8, 64);

    if (lane == 0)
        out[row] = v + sb + pb + GLOBAL_MEAN;
}

extern "C" void kernel_launch(void* const* d_in, const int* in_sizes, int n_in,
                              void* d_out, int out_size, void* d_ws, size_t ws_size,
                              hipStream_t stream) {
    const int* scientist_ids = (const int*)d_in[0];
    const int* paper_ids     = (const int*)d_in[1];
    const int* sp_idx        = (const int*)d_in[2];
    const int* sp_seg        = (const int*)d_in[3];
    const int* sw_idx        = (const int*)d_in[4];
    const int* sw_seg        = (const int*)d_in[5];
    const float* s_factors   = (const float*)d_in[6];
    const float* p_factors   = (const float*)d_in[7];
    const float* s_bias      = (const float*)d_in[8];
    const float* p_bias      = (const float*)d_in[9];
    const float* imp_f       = (const float*)d_in[10];
    const float* imp_w       = (const float*)d_in[11];
    float* out = (float*)d_out;

    const int t_sp = in_sizes[2];
    const int t_sw = in_sizes[4];
    const int tbl_elems = in_sizes[10];            // n_papers * 64

    // ws layout:
    // [0,256)          f32 zero row (64 floats)
    // [256,384)        bf16 zero row (64 u16)
    // [512, ...)       sp_start[(B+1)], sw_start[(B+1)]
    // aligned 256:     bf16 table f16, bf16 table w16
    char* ws = (char*)d_ws;
    float* zrowf  = (float*)ws;
    u16*   zrow16 = (u16*)(ws + 256);
    int* sp_start = (int*)(ws + 512);
    int* sw_start = sp_start + (BATCH + 1);
    size_t off = 512 + (size_t)2 * (BATCH + 1) * 4;
    off = (off + 255) & ~(size_t)255;
    u16* f16 = (u16*)(ws + off);
    u16* w16 = f16 + (size_t)tbl_elems;
    size_t need = off + (size_t)2 * tbl_elems * 2;

    seg_bounds_fused<<<(t_sp + t_sw + 255) / 256, 256, 0, stream>>>(
        sp_seg, t_sp, sp_start, sw_seg, t_sw, sw_start, zrowf);

    const int blocks = (BATCH * 64) / 256;

    if (ws_size >= need) {
        const int cthreads = (tbl_elems >> 2) * 2;   // float4 chunks, both tables
        convert_bf16<<<(cthreads + 255) / 256, 256, 0, stream>>>(
            imp_f, imp_w, f16, w16, tbl_elems, zrow16);
        svdpp_fwd_bf16<<<blocks, 256, 0, stream>>>(
            scientist_ids, paper_ids,
            sp_idx, sp_start, sw_idx, sw_start,
            s_factors, p_factors, s_bias, p_bias,
            f16, w16, zrow16, out);
    } else {
        svdpp_fwd_f32<<<blocks, 256, 0, stream>>>(
            scientist_ids, paper_ids,
            sp_idx, sp_start, sw_idx, sw_start,
            s_factors, p_factors, s_bias, p_bias,
            imp_f, imp_w, zrowf, out);
    }
}